// Round 6
// baseline (412.840 us; speedup 1.0000x reference)
//
#include <hip/hip_runtime.h>

// MuliHeadedMaskedSelfAttention: B=2, T=2048, C=1024, H=16, DK=64, OUT=1024
// Logit path (Q/K projection, QK^T) in split-bf16 (3-term MFMA) for fp32-class
// accuracy; V/P/O plain bf16. Q (ONLY Q) pre-scaled by 8 = sqrt(d_k) multiply.
// Attention: TWO-PASS offset softmax — pass1 hi-only QK^T -> per-lane max
// (no cross-lane ops in loop), m_hat = max+2; pass2 fixed-offset exp, no
// rescaling, li reduced once at end. 64-key steps, 1-wave blocks, longest-first.

typedef unsigned short u16;
typedef unsigned int u32;
typedef __attribute__((ext_vector_type(8))) short bf16x8;
typedef __attribute__((ext_vector_type(4))) float f32x4;

__device__ inline u16 f2bf(float f) {
  union { float f; unsigned u; } v; v.f = f;
  unsigned r = v.u + 0x7FFFu + ((v.u >> 16) & 1u);  // RNE
  return (u16)(r >> 16);
}
__device__ inline float bf2f(u16 h) {
  union { unsigned u; float f; } v; v.u = ((unsigned)h) << 16;
  return v.f;
}
__device__ inline void glds16(const u16* g, u16* s) {
  __builtin_amdgcn_global_load_lds(
      (const __attribute__((address_space(1))) u32*)g,
      (__attribute__((address_space(3))) u32*)s, 16, 0, 0);
}
#define MFMA __builtin_amdgcn_mfma_f32_16x16x32_bf16

// ---- split-cast fp32 -> (hi, lo) bf16, 4 elems/thread
__global__ __launch_bounds__(256) void split_cast(const float* __restrict__ src,
                                                  u16* __restrict__ hi,
                                                  u16* __restrict__ lo, int n) {
  int i = (blockIdx.x * 256 + threadIdx.x) * 4;
  if (i >= n) return;
  float4 v = *(const float4*)(src + i);
  ushort4 h, l;
  h.x = f2bf(v.x); l.x = f2bf(v.x - bf2f(h.x));
  h.y = f2bf(v.y); l.y = f2bf(v.y - bf2f(h.y));
  h.z = f2bf(v.z); l.z = f2bf(v.z - bf2f(h.z));
  h.w = f2bf(v.w); l.w = f2bf(v.w - bf2f(h.w));
  *(ushort4*)(hi + i) = h;
  *(ushort4*)(lo + i) = l;
}

// ---- transpose 1024x1024 fp32 -> bf16 (Wt[n][c] = W[c][n])
__global__ __launch_bounds__(256) void transpose_cast(const float* __restrict__ W,
                                                      u16* __restrict__ Wt) {
  __shared__ float tile[32][33];
  int bx = blockIdx.x * 32, by = blockIdx.y * 32;
  int tx = threadIdx.x, ty = threadIdx.y;
#pragma unroll
  for (int j = 0; j < 32; j += 8)
    tile[ty + j][tx] = W[(size_t)(by + ty + j) * 1024 + bx + tx];
  __syncthreads();
#pragma unroll
  for (int j = 0; j < 32; j += 8)
    Wt[(size_t)(bx + ty + j) * 1024 + by + tx] = f2bf(tile[tx][ty + j]);
}

// ---- transpose + split-cast
__global__ __launch_bounds__(256) void transpose_cast_split(const float* __restrict__ W,
                                                            u16* __restrict__ Wth,
                                                            u16* __restrict__ Wtl) {
  __shared__ float tile[32][33];
  int bx = blockIdx.x * 32, by = blockIdx.y * 32;
  int tx = threadIdx.x, ty = threadIdx.y;
#pragma unroll
  for (int j = 0; j < 32; j += 8)
    tile[ty + j][tx] = W[(size_t)(by + ty + j) * 1024 + bx + tx];
  __syncthreads();
#pragma unroll
  for (int j = 0; j < 32; j += 8) {
    float v = tile[tx][ty + j];
    u16 h = f2bf(v);
    size_t idx = (size_t)(bx + ty + j) * 1024 + by + tx;
    Wth[idx] = h;
    Wtl[idx] = f2bf(v - bf2f(h));
  }
}

// ---- fused QKV projection. 128x128 tile, BK=32, global_load_lds staging.
// z=0: Q (split, scale 8, hi/lo out), z=1: K (split, NO scale), z=2: V (plain, V^T out).
__global__ __launch_bounds__(256) void gemm_qkv(
    const u16* __restrict__ Xh, const u16* __restrict__ Xl,
    const u16* __restrict__ Wqh, const u16* __restrict__ Wql,
    const u16* __restrict__ Wkh, const u16* __restrict__ Wkl,
    const u16* __restrict__ Wvt,
    u16* __restrict__ Qh, u16* __restrict__ Ql,
    u16* __restrict__ Kh, u16* __restrict__ Kl,
    u16* __restrict__ Vt) {
  __shared__ u16 S[4][128][32];
  const int K = 1024;
  const int z = blockIdx.z;
  const bool split = (z < 2);
  const u16* Bh = (z == 0) ? Wqh : (z == 1) ? Wkh : Wvt;
  const u16* Bl = (z == 0) ? Wql : Wkl;
  const int tid = threadIdx.x;
  const int lane = tid & 63, wv = tid >> 6;
  const int quad = lane >> 4, lc = lane & 15;
  const int m0 = blockIdx.y * 128, n0 = blockIdx.x * 128;
  const int wm = (wv >> 1) * 64, wn = (wv & 1) * 64;
  const int lrow = lane >> 2, lk = (lane & 3) * 8;
  const u16* a0p = Xh + (size_t)(m0 + wv * 32 + lrow) * K + lk;
  const u16* a1p = a0p + 16 * K;
  const u16* al0p = Xl + (size_t)(m0 + wv * 32 + lrow) * K + lk;
  const u16* al1p = al0p + 16 * K;
  const u16* b0p = Bh + (size_t)(n0 + wv * 32 + lrow) * K + lk;
  const u16* b1p = b0p + 16 * K;
  const u16* bl0p = split ? (Bl + (size_t)(n0 + wv * 32 + lrow) * K + lk) : b0p;
  const u16* bl1p = bl0p + 16 * K;
  u16* sA0 = &S[0][wv * 32][0];      u16* sA1 = &S[0][wv * 32 + 16][0];
  u16* sAl0 = &S[1][wv * 32][0];     u16* sAl1 = &S[1][wv * 32 + 16][0];
  u16* sB0 = &S[2][wv * 32][0];      u16* sB1 = &S[2][wv * 32 + 16][0];
  u16* sBl0 = &S[3][wv * 32][0];     u16* sBl1 = &S[3][wv * 32 + 16][0];
  f32x4 acc[4][4];
#pragma unroll
  for (int i = 0; i < 4; i++)
#pragma unroll
    for (int j = 0; j < 4; j++) acc[i][j] = (f32x4){0.f, 0.f, 0.f, 0.f};
  for (int kc = 0; kc < K; kc += 32) {
    __syncthreads();
    glds16(a0p + kc, sA0); glds16(a1p + kc, sA1);
    glds16(b0p + kc, sB0); glds16(b1p + kc, sB1);
    if (split) {
      glds16(al0p + kc, sAl0); glds16(al1p + kc, sAl1);
      glds16(bl0p + kc, sBl0); glds16(bl1p + kc, sBl1);
    }
    __syncthreads();
    bf16x8 ah[4], al[4];
#pragma unroll
    for (int mt = 0; mt < 4; mt++)
      ah[mt] = *(const bf16x8*)&S[0][wm + mt * 16 + lc][quad * 8];
    if (split) {
#pragma unroll
      for (int mt = 0; mt < 4; mt++)
        al[mt] = *(const bf16x8*)&S[1][wm + mt * 16 + lc][quad * 8];
    }
#pragma unroll
    for (int nt = 0; nt < 4; nt++) {
      bf16x8 bfh = *(const bf16x8*)&S[2][wn + nt * 16 + lc][quad * 8];
#pragma unroll
      for (int mt = 0; mt < 4; mt++)
        acc[mt][nt] = MFMA(ah[mt], bfh, acc[mt][nt], 0, 0, 0);
      if (split) {
        bf16x8 bfl = *(const bf16x8*)&S[3][wn + nt * 16 + lc][quad * 8];
#pragma unroll
        for (int mt = 0; mt < 4; mt++) {
          acc[mt][nt] = MFMA(ah[mt], bfl, acc[mt][nt], 0, 0, 0);
          acc[mt][nt] = MFMA(al[mt], bfh, acc[mt][nt], 0, 0, 0);
        }
      }
    }
  }
  const int rb = quad * 4;
  if (z == 2) {
#pragma unroll
    for (int mt = 0; mt < 4; mt++)
#pragma unroll
      for (int nt = 0; nt < 4; nt++)
#pragma unroll
        for (int r = 0; r < 4; r++) {
          int m = m0 + wm + mt * 16 + rb + r, n = n0 + wn + nt * 16 + lc;
          int b = m >> 11, t = m & 2047, h = n >> 6, d = n & 63;
          Vt[((size_t)(b * 16 + h) * 64 + d) * 2048 + t] = f2bf(acc[mt][nt][r]);
        }
  } else {
    u16* Ch = (z == 0) ? Qh : Kh;
    u16* Cl = (z == 0) ? Ql : Kl;
    const float scale = (z == 0) ? 8.0f : 1.0f;  // fold sqrt(d_k) into Q ONLY
#pragma unroll
    for (int mt = 0; mt < 4; mt++)
#pragma unroll
      for (int nt = 0; nt < 4; nt++)
#pragma unroll
        for (int r = 0; r < 4; r++) {
          int m = m0 + wm + mt * 16 + rb + r, n = n0 + wn + nt * 16 + lc;
          int b = m >> 11, t = m & 2047, h = n >> 6, d = n & 63;
          float v = acc[mt][nt][r] * scale;
          u16 hv = f2bf(v);
          size_t idx = ((size_t)(b * 16 + h) * 2048 + t) * 64 + d;
          Ch[idx] = hv;
          Cl[idx] = f2bf(v - bf2f(hv));
        }
  }
}

// ---- output GEMM: C[4096,1024] fp32 = O16[4096,1024] * Wot[1024,1024]^T.
__global__ __launch_bounds__(256) void gemm_out(const u16* __restrict__ A,
                                                const u16* __restrict__ Bt,
                                                float* __restrict__ C) {
  __shared__ u16 Sa[64][32], Sb[128][32];
  const int K = 1024, N = 1024;
  const int tid = threadIdx.x;
  const int lane = tid & 63, wv = tid >> 6;
  const int quad = lane >> 4, lc = lane & 15;
  const int m0 = blockIdx.y * 64, n0 = blockIdx.x * 128;
  const int wm = (wv >> 1) * 32, wn = (wv & 1) * 64;
  const int lrow = lane >> 2, lk = (lane & 3) * 8;
  const u16* ap = A + (size_t)(m0 + wv * 16 + lrow) * K + lk;
  const u16* b0p = Bt + (size_t)(n0 + wv * 32 + lrow) * K + lk;
  const u16* b1p = b0p + 16 * K;
  u16* sA = &Sa[wv * 16][0];
  u16* sB0 = &Sb[wv * 32][0];
  u16* sB1 = &Sb[wv * 32 + 16][0];
  f32x4 acc[2][4];
#pragma unroll
  for (int i = 0; i < 2; i++)
#pragma unroll
    for (int j = 0; j < 4; j++) acc[i][j] = (f32x4){0.f, 0.f, 0.f, 0.f};
  for (int kc = 0; kc < K; kc += 32) {
    __syncthreads();
    glds16(ap + kc, sA);
    glds16(b0p + kc, sB0);
    glds16(b1p + kc, sB1);
    __syncthreads();
    bf16x8 ah[2];
#pragma unroll
    for (int mt = 0; mt < 2; mt++)
      ah[mt] = *(const bf16x8*)&Sa[wm + mt * 16 + lc][quad * 8];
#pragma unroll
    for (int nt = 0; nt < 4; nt++) {
      bf16x8 bfh = *(const bf16x8*)&Sb[wn + nt * 16 + lc][quad * 8];
#pragma unroll
      for (int mt = 0; mt < 2; mt++)
        acc[mt][nt] = MFMA(ah[mt], bfh, acc[mt][nt], 0, 0, 0);
    }
  }
#pragma unroll
  for (int mt = 0; mt < 2; mt++)
#pragma unroll
    for (int nt = 0; nt < 4; nt++)
#pragma unroll
      for (int r = 0; r < 4; r++)
        C[(size_t)(m0 + wm + mt * 16 + quad * 4 + r) * N + n0 + wn + nt * 16 + lc] =
            acc[mt][nt][r];
}

// ---- flash attention v2: two-pass offset softmax, 64-key groups,
// 1 wave per block, longest-first, no per-step cross-lane ops.
__global__ __launch_bounds__(64) void attn(const u16* __restrict__ Qh,
                                           const u16* __restrict__ Ql,
                                           const u16* __restrict__ Kh,
                                           const u16* __restrict__ Kl,
                                           const u16* __restrict__ Vt,
                                           u16* __restrict__ O16) {
  __shared__ u16 Ps[16][72];  // 144B row stride (16B-aligned; 2-way banks = free)
  const int lane = threadIdx.x;
  const int quad = lane >> 4, lc = lane & 15;
  const int bh = blockIdx.x & 31;
  const int qt = 127 - (blockIdx.x >> 5);  // longest first
  const int t0 = qt * 16;
  const int ng = (qt >> 2) + 1;  // 64-key groups covering t0+16 keys
  const size_t kbase = (size_t)bh * 2048 * 64;
  const size_t vbase = (size_t)bh * 64 * 2048;
  const size_t qoff = kbase + (size_t)(t0 + lc) * 64 + quad * 8;
  bf16x8 qh0 = *(const bf16x8*)(Qh + qoff);
  bf16x8 qh1 = *(const bf16x8*)(Qh + qoff + 32);
  bf16x8 ql0 = *(const bf16x8*)(Ql + qoff);
  bf16x8 ql1 = *(const bf16x8*)(Ql + qoff + 32);
  const int gtr = t0 + quad * 4;  // this lane's score rows are gtr..gtr+3

  // ---- pass 1: per-lane approximate row max (hi-only QK), no cross-lane ops
  f32x4 mx = (f32x4){-3.0e38f, -3.0e38f, -3.0e38f, -3.0e38f};
  for (int g = 0; g < ng; g++) {
    int z0 = g * 64;
    bool fin = (g == ng - 1);
#pragma unroll
    for (int t = 0; t < 4; t++) {
      int col = z0 + t * 16 + lc;
      int zr = col > 2047 ? 2047 : col;
      const u16* p = Kh + kbase + (size_t)zr * 64 + quad * 8;
      bf16x8 k0 = *(const bf16x8*)p;
      bf16x8 k1 = *(const bf16x8*)(p + 32);
      f32x4 s = (f32x4){0.f, 0.f, 0.f, 0.f};
      s = MFMA(qh0, k0, s, 0, 0, 0);
      s = MFMA(qh1, k1, s, 0, 0, 0);
      if (fin) {
#pragma unroll
        for (int r = 0; r < 4; r++)
          if (col > gtr + r) s[r] = -3.0e38f;
      }
#pragma unroll
      for (int r = 0; r < 4; r++) mx[r] = fmaxf(mx[r], s[r]);
    }
  }
  float mhat[4];
#pragma unroll
  for (int r = 0; r < 4; r++) {
    float m = mx[r];
#pragma unroll
    for (int off = 1; off < 16; off <<= 1) m = fmaxf(m, __shfl_xor(m, off));
    mhat[r] = m + 2.0f;  // margin: covers hi-only approx error; softmax is
  }                      // offset-invariant so any safe m_hat is exact

  // ---- pass 2: fixed-offset exp, no rescaling, per-lane li accumulation
  f32x4 o[4];
#pragma unroll
  for (int i = 0; i < 4; i++) o[i] = (f32x4){0.f, 0.f, 0.f, 0.f};
  f32x4 li = (f32x4){0.f, 0.f, 0.f, 0.f};
  for (int g = 0; g < ng; g++) {
    int z0 = g * 64;
    bool fin = (g == ng - 1);
    bf16x8 vf[4][2];
#pragma unroll
    for (int dt = 0; dt < 4; dt++) {
      const u16* vp = Vt + vbase + (size_t)(dt * 16 + lc) * 2048 + z0 + quad * 8;
      vf[dt][0] = *(const bf16x8*)vp;
      vf[dt][1] = *(const bf16x8*)(vp + 32);
    }
#pragma unroll
    for (int t = 0; t < 4; t++) {
      int col = z0 + t * 16 + lc;
      int zr = col > 2047 ? 2047 : col;
      const u16* ph = Kh + kbase + (size_t)zr * 64 + quad * 8;
      const u16* pl = Kl + kbase + (size_t)zr * 64 + quad * 8;
      bf16x8 kh0 = *(const bf16x8*)ph, kh1 = *(const bf16x8*)(ph + 32);
      bf16x8 kl0 = *(const bf16x8*)pl, kl1 = *(const bf16x8*)(pl + 32);
      f32x4 s = (f32x4){0.f, 0.f, 0.f, 0.f};
      s = MFMA(qh0, kh0, s, 0, 0, 0);
      s = MFMA(qh1, kh1, s, 0, 0, 0);
      s = MFMA(qh0, kl0, s, 0, 0, 0);
      s = MFMA(qh1, kl1, s, 0, 0, 0);
      s = MFMA(ql0, kh0, s, 0, 0, 0);
      s = MFMA(ql1, kh1, s, 0, 0, 0);
      if (fin) {
#pragma unroll
        for (int r = 0; r < 4; r++)
          if (col > gtr + r) s[r] = -3.0e38f;
      }
#pragma unroll
      for (int r = 0; r < 4; r++) {
        float p = __expf(s[r] - mhat[r]);  // masked -> exp(-huge) = 0
        li[r] += p;
        Ps[quad * 4 + r][t * 16 + lc] = f2bf(p);
      }
    }
    // C-layout -> A-layout roundtrip (per-wave LDS; DS ops in-order per wave)
    bf16x8 pf0 = *(const bf16x8*)&Ps[lc][quad * 8];
    bf16x8 pf1 = *(const bf16x8*)&Ps[lc][32 + quad * 8];
#pragma unroll
    for (int dt = 0; dt < 4; dt++) {
      o[dt] = MFMA(pf0, vf[dt][0], o[dt], 0, 0, 0);
      o[dt] = MFMA(pf1, vf[dt][1], o[dt], 0, 0, 0);
    }
  }
  // single end-of-kernel cross-lane sum for the denominator
#pragma unroll
  for (int r = 0; r < 4; r++) {
    float s = li[r];
#pragma unroll
    for (int off = 1; off < 16; off <<= 1) s += __shfl_xor(s, off);
    li[r] = s;
  }
  const int b = bh >> 4, h = bh & 15;
#pragma unroll
  for (int dt = 0; dt < 4; dt++)
#pragma unroll
    for (int r = 0; r < 4; r++) {
      int t = t0 + quad * 4 + r;
      O16[((size_t)(b * 2048 + t)) * 1024 + h * 64 + dt * 16 + lc] =
          f2bf(o[dt][r] / li[r]);
    }
}

extern "C" void kernel_launch(void* const* d_in, const int* in_sizes, int n_in,
                              void* d_out, int out_size, void* d_ws, size_t ws_size,
                              hipStream_t stream) {
  const float* x  = (const float*)d_in[0];
  const float* wq = (const float*)d_in[1];
  const float* wk = (const float*)d_in[2];
  const float* wv = (const float*)d_in[3];
  const float* wo = (const float*)d_in[4];

  char* w = (char*)d_ws;
  const size_t MB = 1u << 20;
  u16* Xh  = (u16*)(w + 0 * MB);   // 8MB; dead after projections -> O16 reuses
  u16* Xl  = (u16*)(w + 8 * MB);
  u16* Wqh = (u16*)(w + 16 * MB);
  u16* Wql = (u16*)(w + 18 * MB);
  u16* Wkh = (u16*)(w + 20 * MB);
  u16* Wkl = (u16*)(w + 22 * MB);
  u16* Wvt = (u16*)(w + 24 * MB);
  u16* Wot = (u16*)(w + 26 * MB);
  u16* Qhb = (u16*)(w + 28 * MB);  // [32][2048][64] bf16
  u16* Qlb = (u16*)(w + 36 * MB);
  u16* Khb = (u16*)(w + 44 * MB);
  u16* Klb = (u16*)(w + 52 * MB);
  u16* Vtb = (u16*)(w + 60 * MB);  // [32][64][2048] bf16
  u16* O16 = (u16*)(w + 0 * MB);   // reuse Xh region

  hipLaunchKernelGGL(split_cast, dim3(4096), dim3(256), 0, stream, x, Xh, Xl, 4194304);
  dim3 tb(32, 8), tg(32, 32);
  hipLaunchKernelGGL(transpose_cast_split, tg, tb, 0, stream, wq, Wqh, Wql);
  hipLaunchKernelGGL(transpose_cast_split, tg, tb, 0, stream, wk, Wkh, Wkl);
  hipLaunchKernelGGL(transpose_cast, tg, tb, 0, stream, wv, Wvt);
  hipLaunchKernelGGL(transpose_cast, tg, tb, 0, stream, wo, Wot);

  hipLaunchKernelGGL(gemm_qkv, dim3(8, 32, 3), dim3(256), 0, stream,
                     Xh, Xl, Wqh, Wql, Wkh, Wkl, Wvt, Qhb, Qlb, Khb, Klb, Vtb);

  hipLaunchKernelGGL(attn, dim3(4096), dim3(64), 0, stream,
                     Qhb, Qlb, Khb, Klb, Vtb, O16);

  hipLaunchKernelGGL(gemm_out, dim3(8, 64), dim3(256), 0, stream, O16, Wot, (float*)d_out);
}

// Round 7
// 407.017 us; speedup vs baseline: 1.0143x; 1.0143x over previous
//
#include <hip/hip_runtime.h>

// MuliHeadedMaskedSelfAttention: B=2, T=2048, C=1024, H=16, DK=64, OUT=1024
// Logit path (Q/K projection, QK^T) in split-bf16 (3-term MFMA) for fp32-class
// accuracy; V/P/O plain bf16. Q (ONLY Q) pre-scaled by 8 = sqrt(d_k) multiply.
// Attention v4: two-pass offset softmax, 64-key groups, 1-wave blocks,
// __launch_bounds__(64,2) for a 256-VGPR budget, ALL group loads hoisted
// (24 outstanding), XCD-swizzled bh for L2 locality, longest-first.

typedef unsigned short u16;
typedef unsigned int u32;
typedef __attribute__((ext_vector_type(8))) short bf16x8;
typedef __attribute__((ext_vector_type(4))) float f32x4;

__device__ inline u16 f2bf(float f) {
  union { float f; unsigned u; } v; v.f = f;
  unsigned r = v.u + 0x7FFFu + ((v.u >> 16) & 1u);  // RNE
  return (u16)(r >> 16);
}
__device__ inline float bf2f(u16 h) {
  union { unsigned u; float f; } v; v.u = ((unsigned)h) << 16;
  return v.f;
}
__device__ inline void glds16(const u16* g, u16* s) {
  __builtin_amdgcn_global_load_lds(
      (const __attribute__((address_space(1))) u32*)g,
      (__attribute__((address_space(3))) u32*)s, 16, 0, 0);
}
#define MFMA __builtin_amdgcn_mfma_f32_16x16x32_bf16

// ---- split-cast fp32 -> (hi, lo) bf16, 4 elems/thread
__global__ __launch_bounds__(256) void split_cast(const float* __restrict__ src,
                                                  u16* __restrict__ hi,
                                                  u16* __restrict__ lo, int n) {
  int i = (blockIdx.x * 256 + threadIdx.x) * 4;
  if (i >= n) return;
  float4 v = *(const float4*)(src + i);
  ushort4 h, l;
  h.x = f2bf(v.x); l.x = f2bf(v.x - bf2f(h.x));
  h.y = f2bf(v.y); l.y = f2bf(v.y - bf2f(h.y));
  h.z = f2bf(v.z); l.z = f2bf(v.z - bf2f(h.z));
  h.w = f2bf(v.w); l.w = f2bf(v.w - bf2f(h.w));
  *(ushort4*)(hi + i) = h;
  *(ushort4*)(lo + i) = l;
}

// ---- transpose 1024x1024 fp32 -> bf16 (Wt[n][c] = W[c][n])
__global__ __launch_bounds__(256) void transpose_cast(const float* __restrict__ W,
                                                      u16* __restrict__ Wt) {
  __shared__ float tile[32][33];
  int bx = blockIdx.x * 32, by = blockIdx.y * 32;
  int tx = threadIdx.x, ty = threadIdx.y;
#pragma unroll
  for (int j = 0; j < 32; j += 8)
    tile[ty + j][tx] = W[(size_t)(by + ty + j) * 1024 + bx + tx];
  __syncthreads();
#pragma unroll
  for (int j = 0; j < 32; j += 8)
    Wt[(size_t)(bx + ty + j) * 1024 + by + tx] = f2bf(tile[tx][ty + j]);
}

// ---- transpose + split-cast
__global__ __launch_bounds__(256) void transpose_cast_split(const float* __restrict__ W,
                                                            u16* __restrict__ Wth,
                                                            u16* __restrict__ Wtl) {
  __shared__ float tile[32][33];
  int bx = blockIdx.x * 32, by = blockIdx.y * 32;
  int tx = threadIdx.x, ty = threadIdx.y;
#pragma unroll
  for (int j = 0; j < 32; j += 8)
    tile[ty + j][tx] = W[(size_t)(by + ty + j) * 1024 + bx + tx];
  __syncthreads();
#pragma unroll
  for (int j = 0; j < 32; j += 8) {
    float v = tile[tx][ty + j];
    u16 h = f2bf(v);
    size_t idx = (size_t)(bx + ty + j) * 1024 + by + tx;
    Wth[idx] = h;
    Wtl[idx] = f2bf(v - bf2f(h));
  }
}

// ---- fused QKV projection. 128x128 tile, BK=32, global_load_lds staging.
// z=0: Q (split, scale 8, hi/lo out), z=1: K (split, NO scale), z=2: V (plain, V^T out).
__global__ __launch_bounds__(256) void gemm_qkv(
    const u16* __restrict__ Xh, const u16* __restrict__ Xl,
    const u16* __restrict__ Wqh, const u16* __restrict__ Wql,
    const u16* __restrict__ Wkh, const u16* __restrict__ Wkl,
    const u16* __restrict__ Wvt,
    u16* __restrict__ Qh, u16* __restrict__ Ql,
    u16* __restrict__ Kh, u16* __restrict__ Kl,
    u16* __restrict__ Vt) {
  __shared__ u16 S[4][128][32];
  const int K = 1024;
  const int z = blockIdx.z;
  const bool split = (z < 2);
  const u16* Bh = (z == 0) ? Wqh : (z == 1) ? Wkh : Wvt;
  const u16* Bl = (z == 0) ? Wql : Wkl;
  const int tid = threadIdx.x;
  const int lane = tid & 63, wv = tid >> 6;
  const int quad = lane >> 4, lc = lane & 15;
  const int m0 = blockIdx.y * 128, n0 = blockIdx.x * 128;
  const int wm = (wv >> 1) * 64, wn = (wv & 1) * 64;
  const int lrow = lane >> 2, lk = (lane & 3) * 8;
  const u16* a0p = Xh + (size_t)(m0 + wv * 32 + lrow) * K + lk;
  const u16* a1p = a0p + 16 * K;
  const u16* al0p = Xl + (size_t)(m0 + wv * 32 + lrow) * K + lk;
  const u16* al1p = al0p + 16 * K;
  const u16* b0p = Bh + (size_t)(n0 + wv * 32 + lrow) * K + lk;
  const u16* b1p = b0p + 16 * K;
  const u16* bl0p = split ? (Bl + (size_t)(n0 + wv * 32 + lrow) * K + lk) : b0p;
  const u16* bl1p = bl0p + 16 * K;
  u16* sA0 = &S[0][wv * 32][0];      u16* sA1 = &S[0][wv * 32 + 16][0];
  u16* sAl0 = &S[1][wv * 32][0];     u16* sAl1 = &S[1][wv * 32 + 16][0];
  u16* sB0 = &S[2][wv * 32][0];      u16* sB1 = &S[2][wv * 32 + 16][0];
  u16* sBl0 = &S[3][wv * 32][0];     u16* sBl1 = &S[3][wv * 32 + 16][0];
  f32x4 acc[4][4];
#pragma unroll
  for (int i = 0; i < 4; i++)
#pragma unroll
    for (int j = 0; j < 4; j++) acc[i][j] = (f32x4){0.f, 0.f, 0.f, 0.f};
  for (int kc = 0; kc < K; kc += 32) {
    __syncthreads();
    glds16(a0p + kc, sA0); glds16(a1p + kc, sA1);
    glds16(b0p + kc, sB0); glds16(b1p + kc, sB1);
    if (split) {
      glds16(al0p + kc, sAl0); glds16(al1p + kc, sAl1);
      glds16(bl0p + kc, sBl0); glds16(bl1p + kc, sBl1);
    }
    __syncthreads();
    bf16x8 ah[4], al[4];
#pragma unroll
    for (int mt = 0; mt < 4; mt++)
      ah[mt] = *(const bf16x8*)&S[0][wm + mt * 16 + lc][quad * 8];
    if (split) {
#pragma unroll
      for (int mt = 0; mt < 4; mt++)
        al[mt] = *(const bf16x8*)&S[1][wm + mt * 16 + lc][quad * 8];
    }
#pragma unroll
    for (int nt = 0; nt < 4; nt++) {
      bf16x8 bfh = *(const bf16x8*)&S[2][wn + nt * 16 + lc][quad * 8];
#pragma unroll
      for (int mt = 0; mt < 4; mt++)
        acc[mt][nt] = MFMA(ah[mt], bfh, acc[mt][nt], 0, 0, 0);
      if (split) {
        bf16x8 bfl = *(const bf16x8*)&S[3][wn + nt * 16 + lc][quad * 8];
#pragma unroll
        for (int mt = 0; mt < 4; mt++) {
          acc[mt][nt] = MFMA(ah[mt], bfl, acc[mt][nt], 0, 0, 0);
          acc[mt][nt] = MFMA(al[mt], bfh, acc[mt][nt], 0, 0, 0);
        }
      }
    }
  }
  const int rb = quad * 4;
  if (z == 2) {
#pragma unroll
    for (int mt = 0; mt < 4; mt++)
#pragma unroll
      for (int nt = 0; nt < 4; nt++)
#pragma unroll
        for (int r = 0; r < 4; r++) {
          int m = m0 + wm + mt * 16 + rb + r, n = n0 + wn + nt * 16 + lc;
          int b = m >> 11, t = m & 2047, h = n >> 6, d = n & 63;
          Vt[((size_t)(b * 16 + h) * 64 + d) * 2048 + t] = f2bf(acc[mt][nt][r]);
        }
  } else {
    u16* Ch = (z == 0) ? Qh : Kh;
    u16* Cl = (z == 0) ? Ql : Kl;
    const float scale = (z == 0) ? 8.0f : 1.0f;  // fold sqrt(d_k) into Q ONLY
#pragma unroll
    for (int mt = 0; mt < 4; mt++)
#pragma unroll
      for (int nt = 0; nt < 4; nt++)
#pragma unroll
        for (int r = 0; r < 4; r++) {
          int m = m0 + wm + mt * 16 + rb + r, n = n0 + wn + nt * 16 + lc;
          int b = m >> 11, t = m & 2047, h = n >> 6, d = n & 63;
          float v = acc[mt][nt][r] * scale;
          u16 hv = f2bf(v);
          size_t idx = ((size_t)(b * 16 + h) * 2048 + t) * 64 + d;
          Ch[idx] = hv;
          Cl[idx] = f2bf(v - bf2f(hv));
        }
  }
}

// ---- output GEMM: C[4096,1024] fp32 = O16[4096,1024] * Wot[1024,1024]^T.
__global__ __launch_bounds__(256) void gemm_out(const u16* __restrict__ A,
                                                const u16* __restrict__ Bt,
                                                float* __restrict__ C) {
  __shared__ u16 Sa[64][32], Sb[128][32];
  const int K = 1024, N = 1024;
  const int tid = threadIdx.x;
  const int lane = tid & 63, wv = tid >> 6;
  const int quad = lane >> 4, lc = lane & 15;
  const int m0 = blockIdx.y * 64, n0 = blockIdx.x * 128;
  const int wm = (wv >> 1) * 32, wn = (wv & 1) * 64;
  const int lrow = lane >> 2, lk = (lane & 3) * 8;
  const u16* ap = A + (size_t)(m0 + wv * 16 + lrow) * K + lk;
  const u16* b0p = Bt + (size_t)(n0 + wv * 32 + lrow) * K + lk;
  const u16* b1p = b0p + 16 * K;
  u16* sA = &Sa[wv * 16][0];
  u16* sB0 = &Sb[wv * 32][0];
  u16* sB1 = &Sb[wv * 32 + 16][0];
  f32x4 acc[2][4];
#pragma unroll
  for (int i = 0; i < 2; i++)
#pragma unroll
    for (int j = 0; j < 4; j++) acc[i][j] = (f32x4){0.f, 0.f, 0.f, 0.f};
  for (int kc = 0; kc < K; kc += 32) {
    __syncthreads();
    glds16(ap + kc, sA);
    glds16(b0p + kc, sB0);
    glds16(b1p + kc, sB1);
    __syncthreads();
    bf16x8 ah[2];
#pragma unroll
    for (int mt = 0; mt < 2; mt++)
      ah[mt] = *(const bf16x8*)&Sa[wm + mt * 16 + lc][quad * 8];
#pragma unroll
    for (int nt = 0; nt < 4; nt++) {
      bf16x8 bfh = *(const bf16x8*)&Sb[wn + nt * 16 + lc][quad * 8];
#pragma unroll
      for (int mt = 0; mt < 2; mt++)
        acc[mt][nt] = MFMA(ah[mt], bfh, acc[mt][nt], 0, 0, 0);
    }
  }
#pragma unroll
  for (int mt = 0; mt < 2; mt++)
#pragma unroll
    for (int nt = 0; nt < 4; nt++)
#pragma unroll
      for (int r = 0; r < 4; r++)
        C[(size_t)(m0 + wm + mt * 16 + quad * 4 + r) * N + n0 + wn + nt * 16 + lc] =
            acc[mt][nt][r];
}

// ---- flash attention v4: two-pass offset softmax, 64-key groups, 1-wave
// blocks with (64,2) VGPR budget, all group loads hoisted, XCD-swizzled bh.
__global__ __launch_bounds__(64, 2) void attn(const u16* __restrict__ Qh,
                                              const u16* __restrict__ Ql,
                                              const u16* __restrict__ Kh,
                                              const u16* __restrict__ Kl,
                                              const u16* __restrict__ Vt,
                                              u16* __restrict__ O16) {
  __shared__ u16 Ps[16][72];  // 144B row stride: 16B-aligned, 2-way banks (free)
  const int lane = threadIdx.x;
  const int quad = lane >> 4, lc = lane & 15;
  const int i = blockIdx.x;
  // XCD swizzle: blocks with i%8==c land on XCD c -> each XCD serves 4 heads.
  const int bh = ((i & 7) << 2) | ((i >> 3) & 3);
  const int qt = 127 - (i >> 5);  // longest first
  const int t0 = qt * 16;
  const int ng = (qt >> 2) + 1;   // 64-key groups; col <= 64*(qt>>2)+63 <= 2047
  const size_t kbase = (size_t)bh * 2048 * 64;
  const size_t qoff = kbase + (size_t)(t0 + lc) * 64 + quad * 8;
  bf16x8 qh0 = *(const bf16x8*)(Qh + qoff);
  bf16x8 qh1 = *(const bf16x8*)(Qh + qoff + 32);
  bf16x8 ql0 = *(const bf16x8*)(Ql + qoff);
  bf16x8 ql1 = *(const bf16x8*)(Ql + qoff + 32);
  const int gtr = t0 + quad * 4;  // this lane's score rows are gtr..gtr+3
  // lane-resolved tile base pointers (affine; no clamp needed)
  const u16* kp  = Kh + kbase + (size_t)lc * 64 + quad * 8;
  const u16* klp = Kl + kbase + (size_t)lc * 64 + quad * 8;
  const u16* vp  = Vt + (size_t)bh * 64 * 2048 + (size_t)lc * 2048 + quad * 8;

  // ---- pass 1: per-lane approx row max (hi-only QK), loads hoisted per group
  f32x4 mx = (f32x4){-3.0e38f, -3.0e38f, -3.0e38f, -3.0e38f};
  for (int g = 0; g < ng; g++) {
    const int z0 = g * 64;
    const bool fin = (g == ng - 1);
    bf16x8 kb[4][2];
#pragma unroll
    for (int t = 0; t < 4; t++) {
      const u16* p = kp + (size_t)(z0 + t * 16) * 64;
      kb[t][0] = *(const bf16x8*)p;
      kb[t][1] = *(const bf16x8*)(p + 32);
    }
#pragma unroll
    for (int t = 0; t < 4; t++) {
      f32x4 s = (f32x4){0.f, 0.f, 0.f, 0.f};
      s = MFMA(qh0, kb[t][0], s, 0, 0, 0);
      s = MFMA(qh1, kb[t][1], s, 0, 0, 0);
      const int col = z0 + t * 16 + lc;
      if (fin) {
#pragma unroll
        for (int r = 0; r < 4; r++)
          if (col > gtr + r) s[r] = -3.0e38f;
      }
#pragma unroll
      for (int r = 0; r < 4; r++) mx[r] = fmaxf(mx[r], s[r]);
    }
  }
  float mhat[4];
#pragma unroll
  for (int r = 0; r < 4; r++) {
    float m = mx[r];
#pragma unroll
    for (int off = 1; off < 16; off <<= 1) m = fmaxf(m, __shfl_xor(m, off));
    mhat[r] = m + 2.0f;  // margin covers hi-only approx error; offset-invariant
  }

  // ---- pass 2: fixed-offset exp, no rescaling; 24 loads hoisted per group
  f32x4 o[4];
#pragma unroll
  for (int d = 0; d < 4; d++) o[d] = (f32x4){0.f, 0.f, 0.f, 0.f};
  f32x4 li = (f32x4){0.f, 0.f, 0.f, 0.f};
  for (int g = 0; g < ng; g++) {
    const int z0 = g * 64;
    const bool fin = (g == ng - 1);
    bf16x8 kb[4][4];  // [tile][kh0,kh1,kl0,kl1]
#pragma unroll
    for (int t = 0; t < 4; t++) {
      const u16* ph = kp + (size_t)(z0 + t * 16) * 64;
      const u16* pl = klp + (size_t)(z0 + t * 16) * 64;
      kb[t][0] = *(const bf16x8*)ph;
      kb[t][1] = *(const bf16x8*)(ph + 32);
      kb[t][2] = *(const bf16x8*)pl;
      kb[t][3] = *(const bf16x8*)(pl + 32);
    }
    bf16x8 vb[4][2];
#pragma unroll
    for (int dt = 0; dt < 4; dt++) {
      const u16* pv = vp + (size_t)(dt * 16) * 2048 + z0;
      vb[dt][0] = *(const bf16x8*)pv;
      vb[dt][1] = *(const bf16x8*)(pv + 32);
    }
#pragma unroll
    for (int t = 0; t < 4; t++) {
      f32x4 s = (f32x4){0.f, 0.f, 0.f, 0.f};
      s = MFMA(qh0, kb[t][0], s, 0, 0, 0);
      s = MFMA(qh1, kb[t][1], s, 0, 0, 0);
      s = MFMA(qh0, kb[t][2], s, 0, 0, 0);
      s = MFMA(qh1, kb[t][3], s, 0, 0, 0);
      s = MFMA(ql0, kb[t][0], s, 0, 0, 0);
      s = MFMA(ql1, kb[t][1], s, 0, 0, 0);
      const int col = z0 + t * 16 + lc;
      if (fin) {
#pragma unroll
        for (int r = 0; r < 4; r++)
          if (col > gtr + r) s[r] = -3.0e38f;
      }
#pragma unroll
      for (int r = 0; r < 4; r++) {
        float p = __expf(s[r] - mhat[r]);  // masked -> exp(-huge) = 0
        li[r] += p;
        Ps[quad * 4 + r][t * 16 + lc] = f2bf(p);
      }
    }
    // C-layout -> A-layout roundtrip; same-wave DS ops are in-order, so the
    // next group's writes can't bypass these reads.
    bf16x8 pf0 = *(const bf16x8*)&Ps[lc][quad * 8];
    bf16x8 pf1 = *(const bf16x8*)&Ps[lc][32 + quad * 8];
#pragma unroll
    for (int dt = 0; dt < 4; dt++) {
      o[dt] = MFMA(pf0, vb[dt][0], o[dt], 0, 0, 0);
      o[dt] = MFMA(pf1, vb[dt][1], o[dt], 0, 0, 0);
    }
  }
  // single end-of-kernel cross-lane sum for the denominator
#pragma unroll
  for (int r = 0; r < 4; r++) {
    float s = li[r];
#pragma unroll
    for (int off = 1; off < 16; off <<= 1) s += __shfl_xor(s, off);
    li[r] = s;
  }
  const int b = bh >> 4, h = bh & 15;
#pragma unroll
  for (int dt = 0; dt < 4; dt++)
#pragma unroll
    for (int r = 0; r < 4; r++) {
      int t = t0 + quad * 4 + r;
      O16[((size_t)(b * 2048 + t)) * 1024 + h * 64 + dt * 16 + lc] =
          f2bf(o[dt][r] / li[r]);
    }
}

extern "C" void kernel_launch(void* const* d_in, const int* in_sizes, int n_in,
                              void* d_out, int out_size, void* d_ws, size_t ws_size,
                              hipStream_t stream) {
  const float* x  = (const float*)d_in[0];
  const float* wq = (const float*)d_in[1];
  const float* wk = (const float*)d_in[2];
  const float* wv = (const float*)d_in[3];
  const float* wo = (const float*)d_in[4];

  char* w = (char*)d_ws;
  const size_t MB = 1u << 20;
  u16* Xh  = (u16*)(w + 0 * MB);   // 8MB; dead after projections -> O16 reuses
  u16* Xl  = (u16*)(w + 8 * MB);
  u16* Wqh = (u16*)(w + 16 * MB);
  u16* Wql = (u16*)(w + 18 * MB);
  u16* Wkh = (u16*)(w + 20 * MB);
  u16* Wkl = (u16*)(w + 22 * MB);
  u16* Wvt = (u16*)(w + 24 * MB);
  u16* Wot = (u16*)(w + 26 * MB);
  u16* Qhb = (u16*)(w + 28 * MB);  // [32][2048][64] bf16
  u16* Qlb = (u16*)(w + 36 * MB);
  u16* Khb = (u16*)(w + 44 * MB);
  u16* Klb = (u16*)(w + 52 * MB);
  u16* Vtb = (u16*)(w + 60 * MB);  // [32][64][2048] bf16
  u16* O16 = (u16*)(w + 0 * MB);   // reuse Xh region

  hipLaunchKernelGGL(split_cast, dim3(4096), dim3(256), 0, stream, x, Xh, Xl, 4194304);
  dim3 tb(32, 8), tg(32, 32);
  hipLaunchKernelGGL(transpose_cast_split, tg, tb, 0, stream, wq, Wqh, Wql);
  hipLaunchKernelGGL(transpose_cast_split, tg, tb, 0, stream, wk, Wkh, Wkl);
  hipLaunchKernelGGL(transpose_cast, tg, tb, 0, stream, wv, Wvt);
  hipLaunchKernelGGL(transpose_cast, tg, tb, 0, stream, wo, Wot);

  hipLaunchKernelGGL(gemm_qkv, dim3(8, 32, 3), dim3(256), 0, stream,
                     Xh, Xl, Wqh, Wql, Wkh, Wkl, Wvt, Qhb, Qlb, Khb, Klb, Vtb);

  hipLaunchKernelGGL(attn, dim3(4096), dim3(64), 0, stream,
                     Qhb, Qlb, Khb, Klb, Vtb, O16);

  hipLaunchKernelGGL(gemm_out, dim3(8, 64), dim3(256), 0, stream, O16, Wot, (float*)d_out);
}

// Round 9
// 225.103 us; speedup vs baseline: 1.8340x; 1.8081x over previous
//
#include <hip/hip_runtime.h>

// MuliHeadedMaskedSelfAttention: B=2, T=2048, C=1024, H=16, DK=64, OUT=1024
// Logit path (Q/K projection, QK^T) in split-bf16 (3-term MFMA); V/P/O bf16.
// Q pre-scaled by 8 (faithful sqrt(d_k) MULTIPLY).
// attn v6: transposed tiles (S^T=K*Q^T, O^T=V^T*P^T). Softmax state per-lane
// EXCEPT a 2-shuffle cross-quad max per 64-key group (the 4 quads hold
// disjoint key-quarters of each query's scores — v5 bug). li reduced once at end.

typedef unsigned short u16;
typedef unsigned int u32;
typedef unsigned long long u64;
typedef __attribute__((ext_vector_type(8))) short bf16x8;
typedef __attribute__((ext_vector_type(4))) float f32x4;

__device__ inline u16 f2bf(float f) {
  union { float f; unsigned u; } v; v.f = f;
  unsigned r = v.u + 0x7FFFu + ((v.u >> 16) & 1u);  // RNE
  return (u16)(r >> 16);
}
__device__ inline float bf2f(u16 h) {
  union { unsigned u; float f; } v; v.u = ((unsigned)h) << 16;
  return v.f;
}
__device__ inline void glds16(const u16* g, u16* s) {
  __builtin_amdgcn_global_load_lds(
      (const __attribute__((address_space(1))) u32*)g,
      (__attribute__((address_space(3))) u32*)s, 16, 0, 0);
}
#define MFMA __builtin_amdgcn_mfma_f32_16x16x32_bf16

// ---- split-cast fp32 -> (hi, lo) bf16, 4 elems/thread
__global__ __launch_bounds__(256) void split_cast(const float* __restrict__ src,
                                                  u16* __restrict__ hi,
                                                  u16* __restrict__ lo, int n) {
  int i = (blockIdx.x * 256 + threadIdx.x) * 4;
  if (i >= n) return;
  float4 v = *(const float4*)(src + i);
  ushort4 h, l;
  h.x = f2bf(v.x); l.x = f2bf(v.x - bf2f(h.x));
  h.y = f2bf(v.y); l.y = f2bf(v.y - bf2f(h.y));
  h.z = f2bf(v.z); l.z = f2bf(v.z - bf2f(h.z));
  h.w = f2bf(v.w); l.w = f2bf(v.w - bf2f(h.w));
  *(ushort4*)(hi + i) = h;
  *(ushort4*)(lo + i) = l;
}

// ---- transpose 1024x1024 fp32 -> bf16 (Wt[n][c] = W[c][n])
__global__ __launch_bounds__(256) void transpose_cast(const float* __restrict__ W,
                                                      u16* __restrict__ Wt) {
  __shared__ float tile[32][33];
  int bx = blockIdx.x * 32, by = blockIdx.y * 32;
  int tx = threadIdx.x, ty = threadIdx.y;
#pragma unroll
  for (int j = 0; j < 32; j += 8)
    tile[ty + j][tx] = W[(size_t)(by + ty + j) * 1024 + bx + tx];
  __syncthreads();
#pragma unroll
  for (int j = 0; j < 32; j += 8)
    Wt[(size_t)(bx + ty + j) * 1024 + by + tx] = f2bf(tile[tx][ty + j]);
}

// ---- transpose + split-cast
__global__ __launch_bounds__(256) void transpose_cast_split(const float* __restrict__ W,
                                                            u16* __restrict__ Wth,
                                                            u16* __restrict__ Wtl) {
  __shared__ float tile[32][33];
  int bx = blockIdx.x * 32, by = blockIdx.y * 32;
  int tx = threadIdx.x, ty = threadIdx.y;
#pragma unroll
  for (int j = 0; j < 32; j += 8)
    tile[ty + j][tx] = W[(size_t)(by + ty + j) * 1024 + bx + tx];
  __syncthreads();
#pragma unroll
  for (int j = 0; j < 32; j += 8) {
    float v = tile[tx][ty + j];
    u16 h = f2bf(v);
    size_t idx = (size_t)(bx + ty + j) * 1024 + by + tx;
    Wth[idx] = h;
    Wtl[idx] = f2bf(v - bf2f(h));
  }
}

// ---- fused QKV projection. 128x128 tile, BK=32, global_load_lds staging.
// z=0: Q (split, scale 8), z=1: K (split), z=2: V (plain, V^T out).
__global__ __launch_bounds__(256) void gemm_qkv(
    const u16* __restrict__ Xh, const u16* __restrict__ Xl,
    const u16* __restrict__ Wqh, const u16* __restrict__ Wql,
    const u16* __restrict__ Wkh, const u16* __restrict__ Wkl,
    const u16* __restrict__ Wvt,
    u16* __restrict__ Qh, u16* __restrict__ Ql,
    u16* __restrict__ Kh, u16* __restrict__ Kl,
    u16* __restrict__ Vt) {
  __shared__ u16 S[4][128][32];
  const int K = 1024;
  const int z = blockIdx.z;
  const bool split = (z < 2);
  const u16* Bh = (z == 0) ? Wqh : (z == 1) ? Wkh : Wvt;
  const u16* Bl = (z == 0) ? Wql : Wkl;
  const int tid = threadIdx.x;
  const int lane = tid & 63, wv = tid >> 6;
  const int quad = lane >> 4, lc = lane & 15;
  const int m0 = blockIdx.y * 128, n0 = blockIdx.x * 128;
  const int wm = (wv >> 1) * 64, wn = (wv & 1) * 64;
  const int lrow = lane >> 2, lk = (lane & 3) * 8;
  const u16* a0p = Xh + (size_t)(m0 + wv * 32 + lrow) * K + lk;
  const u16* a1p = a0p + 16 * K;
  const u16* al0p = Xl + (size_t)(m0 + wv * 32 + lrow) * K + lk;
  const u16* al1p = al0p + 16 * K;
  const u16* b0p = Bh + (size_t)(n0 + wv * 32 + lrow) * K + lk;
  const u16* b1p = b0p + 16 * K;
  const u16* bl0p = split ? (Bl + (size_t)(n0 + wv * 32 + lrow) * K + lk) : b0p;
  const u16* bl1p = bl0p + 16 * K;
  u16* sA0 = &S[0][wv * 32][0];      u16* sA1 = &S[0][wv * 32 + 16][0];
  u16* sAl0 = &S[1][wv * 32][0];     u16* sAl1 = &S[1][wv * 32 + 16][0];
  u16* sB0 = &S[2][wv * 32][0];      u16* sB1 = &S[2][wv * 32 + 16][0];
  u16* sBl0 = &S[3][wv * 32][0];     u16* sBl1 = &S[3][wv * 32 + 16][0];
  f32x4 acc[4][4];
#pragma unroll
  for (int i = 0; i < 4; i++)
#pragma unroll
    for (int j = 0; j < 4; j++) acc[i][j] = (f32x4){0.f, 0.f, 0.f, 0.f};
  for (int kc = 0; kc < K; kc += 32) {
    __syncthreads();
    glds16(a0p + kc, sA0); glds16(a1p + kc, sA1);
    glds16(b0p + kc, sB0); glds16(b1p + kc, sB1);
    if (split) {
      glds16(al0p + kc, sAl0); glds16(al1p + kc, sAl1);
      glds16(bl0p + kc, sBl0); glds16(bl1p + kc, sBl1);
    }
    __syncthreads();
    bf16x8 ah[4], al[4];
#pragma unroll
    for (int mt = 0; mt < 4; mt++)
      ah[mt] = *(const bf16x8*)&S[0][wm + mt * 16 + lc][quad * 8];
    if (split) {
#pragma unroll
      for (int mt = 0; mt < 4; mt++)
        al[mt] = *(const bf16x8*)&S[1][wm + mt * 16 + lc][quad * 8];
    }
#pragma unroll
    for (int nt = 0; nt < 4; nt++) {
      bf16x8 bfh = *(const bf16x8*)&S[2][wn + nt * 16 + lc][quad * 8];
#pragma unroll
      for (int mt = 0; mt < 4; mt++)
        acc[mt][nt] = MFMA(ah[mt], bfh, acc[mt][nt], 0, 0, 0);
      if (split) {
        bf16x8 bfl = *(const bf16x8*)&S[3][wn + nt * 16 + lc][quad * 8];
#pragma unroll
        for (int mt = 0; mt < 4; mt++) {
          acc[mt][nt] = MFMA(ah[mt], bfl, acc[mt][nt], 0, 0, 0);
          acc[mt][nt] = MFMA(al[mt], bfh, acc[mt][nt], 0, 0, 0);
        }
      }
    }
  }
  const int rb = quad * 4;
  if (z == 2) {
#pragma unroll
    for (int mt = 0; mt < 4; mt++)
#pragma unroll
      for (int nt = 0; nt < 4; nt++)
#pragma unroll
        for (int r = 0; r < 4; r++) {
          int m = m0 + wm + mt * 16 + rb + r, n = n0 + wn + nt * 16 + lc;
          int b = m >> 11, t = m & 2047, h = n >> 6, d = n & 63;
          Vt[((size_t)(b * 16 + h) * 64 + d) * 2048 + t] = f2bf(acc[mt][nt][r]);
        }
  } else {
    u16* Ch = (z == 0) ? Qh : Kh;
    u16* Cl = (z == 0) ? Ql : Kl;
    const float scale = (z == 0) ? 8.0f : 1.0f;  // fold sqrt(d_k) into Q ONLY
#pragma unroll
    for (int mt = 0; mt < 4; mt++)
#pragma unroll
      for (int nt = 0; nt < 4; nt++)
#pragma unroll
        for (int r = 0; r < 4; r++) {
          int m = m0 + wm + mt * 16 + rb + r, n = n0 + wn + nt * 16 + lc;
          int b = m >> 11, t = m & 2047, h = n >> 6, d = n & 63;
          float v = acc[mt][nt][r] * scale;
          u16 hv = f2bf(v);
          size_t idx = ((size_t)(b * 16 + h) * 2048 + t) * 64 + d;
          Ch[idx] = hv;
          Cl[idx] = f2bf(v - bf2f(hv));
        }
  }
}

// ---- output GEMM: C[4096,1024] fp32 = O16[4096,1024] * Wot[1024,1024]^T.
__global__ __launch_bounds__(256) void gemm_out(const u16* __restrict__ A,
                                                const u16* __restrict__ Bt,
                                                float* __restrict__ C) {
  __shared__ u16 Sa[64][32], Sb[128][32];
  const int K = 1024, N = 1024;
  const int tid = threadIdx.x;
  const int lane = tid & 63, wv = tid >> 6;
  const int quad = lane >> 4, lc = lane & 15;
  const int m0 = blockIdx.y * 64, n0 = blockIdx.x * 128;
  const int wm = (wv >> 1) * 32, wn = (wv & 1) * 64;
  const int lrow = lane >> 2, lk = (lane & 3) * 8;
  const u16* ap = A + (size_t)(m0 + wv * 16 + lrow) * K + lk;
  const u16* b0p = Bt + (size_t)(n0 + wv * 32 + lrow) * K + lk;
  const u16* b1p = b0p + 16 * K;
  u16* sA = &Sa[wv * 16][0];
  u16* sB0 = &Sb[wv * 32][0];
  u16* sB1 = &Sb[wv * 32 + 16][0];
  f32x4 acc[2][4];
#pragma unroll
  for (int i = 0; i < 2; i++)
#pragma unroll
    for (int j = 0; j < 4; j++) acc[i][j] = (f32x4){0.f, 0.f, 0.f, 0.f};
  for (int kc = 0; kc < K; kc += 32) {
    __syncthreads();
    glds16(ap + kc, sA);
    glds16(b0p + kc, sB0);
    glds16(b1p + kc, sB1);
    __syncthreads();
    bf16x8 ah[2];
#pragma unroll
    for (int mt = 0; mt < 2; mt++)
      ah[mt] = *(const bf16x8*)&Sa[wm + mt * 16 + lc][quad * 8];
#pragma unroll
    for (int nt = 0; nt < 4; nt++) {
      bf16x8 bfh = *(const bf16x8*)&Sb[wn + nt * 16 + lc][quad * 8];
#pragma unroll
      for (int mt = 0; mt < 2; mt++)
        acc[mt][nt] = MFMA(ah[mt], bfh, acc[mt][nt], 0, 0, 0);
    }
  }
#pragma unroll
  for (int mt = 0; mt < 2; mt++)
#pragma unroll
    for (int nt = 0; nt < 4; nt++)
#pragma unroll
      for (int r = 0; r < 4; r++)
        C[(size_t)(m0 + wm + mt * 16 + quad * 4 + r) * N + n0 + wn + nt * 16 + lc] =
            acc[mt][nt][r];
}

// ---- flash attention v6: transposed tiles, LDS-staged K/V, 4-wave blocks.
// Cross-quad max (2 shuffles) per group keeps P-normalization consistent
// across the 4 lanes sharing a query; li reduced across quads once at end.
__global__ __launch_bounds__(256, 4) void attn(const u16* __restrict__ Qh,
                                               const u16* __restrict__ Ql,
                                               const u16* __restrict__ Kh,
                                               const u16* __restrict__ Kl,
                                               const u16* __restrict__ Vt,
                                               u16* __restrict__ O16) {
  __shared__ u16 Khs[64][64], Kls[64][64], Vs[64][64];  // LDS[r][c] = glob[r][c^(r&7)]
  __shared__ u16 Ps[4][16][72];                          // [wave][query][key-local]
  const int tid = threadIdx.x;
  const int lane = tid & 63, w = tid >> 6;
  const int quad = lane >> 4, lc = lane & 15;
  const int i = blockIdx.x;
  const int bh = i & 31;            // consecutive blocks -> different XCDs
  const int qb = 31 - (i >> 5);     // longest qb first
  const int ng = qb + 1;            // 64-key groups
  const int tq = qb * 64 + w * 16 + lc;  // THIS LANE'S query row
  const size_t kbase = (size_t)bh * 2048 * 64;
  const size_t vbase = (size_t)bh * 64 * 2048;
  // Q B-frags (B[n=query=lc][k=dim])
  const size_t qoff = kbase + (size_t)tq * 64 + quad * 8;
  bf16x8 qh0 = *(const bf16x8*)(Qh + qoff);
  bf16x8 qh1 = *(const bf16x8*)(Qh + qoff + 32);
  bf16x8 ql0 = *(const bf16x8*)(Ql + qoff);
  bf16x8 ql1 = *(const bf16x8*)(Ql + qoff + 32);
  // staging roles: lane -> (row srow, swizzled chunk scol) of 8-row slabs
  const int srow = lane >> 3;
  const int scol = (lane & 7) ^ srow;
  const u16* kg0 = Kh + kbase + (size_t)(w * 16 + srow) * 64 + scol * 8;
  const u16* kg1 = kg0 + 8 * 64;
  const u16* lg0 = Kl + kbase + (size_t)(w * 16 + srow) * 64 + scol * 8;
  const u16* lg1 = lg0 + 8 * 64;
  const u16* vg0 = Vt + vbase + (size_t)(w * 16 + srow) * 2048 + scol * 8;
  const u16* vg1 = vg0 + 8 * 2048;
  u16* kd0 = &Khs[w * 16][0];      u16* kd1 = &Khs[w * 16 + 8][0];
  u16* ld0 = &Kls[w * 16][0];      u16* ld1 = &Kls[w * 16 + 8][0];
  u16* vd0 = &Vs[w * 16][0];       u16* vd1 = &Vs[w * 16 + 8][0];

  float mi = -3.0e38f, li = 0.f;
  f32x4 o[4];
#pragma unroll
  for (int d = 0; d < 4; d++) o[d] = (f32x4){0.f, 0.f, 0.f, 0.f};
  const int rx = lc & 7;  // read-side XOR component (row&7 = lc&7)

  for (int g = 0; g < ng; g++) {
    const int z0 = g * 64;
    __syncthreads();  // prev group's K/V LDS reads done
    glds16(kg0 + (size_t)z0 * 64, kd0); glds16(kg1 + (size_t)z0 * 64, kd1);
    glds16(lg0 + (size_t)z0 * 64, ld0); glds16(lg1 + (size_t)z0 * 64, ld1);
    glds16(vg0 + z0, vd0);              glds16(vg1 + z0, vd1);
    __syncthreads();  // drains glds (vmcnt) per barrier semantics
    // S^T tiles: rows = keys, cols = queries. Lane holds keys tt*16+quad*4+r.
    f32x4 s[4];
#pragma unroll
    for (int tt = 0; tt < 4; tt++) {
      const int R = tt * 16 + lc;
      bf16x8 kh0 = *(const bf16x8*)&Khs[R][(quad ^ rx) * 8];
      bf16x8 kh1 = *(const bf16x8*)&Khs[R][((4 + quad) ^ rx) * 8];
      bf16x8 kl0 = *(const bf16x8*)&Kls[R][(quad ^ rx) * 8];
      bf16x8 kl1 = *(const bf16x8*)&Kls[R][((4 + quad) ^ rx) * 8];
      f32x4 sv = (f32x4){0.f, 0.f, 0.f, 0.f};
      sv = MFMA(kh0, qh0, sv, 0, 0, 0);
      sv = MFMA(kh1, qh1, sv, 0, 0, 0);
      sv = MFMA(kh0, ql0, sv, 0, 0, 0);
      sv = MFMA(kh1, ql1, sv, 0, 0, 0);
      sv = MFMA(kl0, qh0, sv, 0, 0, 0);
      sv = MFMA(kl1, qh1, sv, 0, 0, 0);
      s[tt] = sv;
    }
    if (g == ng - 1) {  // only the final group straddles the diagonal
#pragma unroll
      for (int tt = 0; tt < 4; tt++)
#pragma unroll
        for (int r = 0; r < 4; r++)
          if (z0 + tt * 16 + quad * 4 + r > tq) s[tt][r] = -3.0e38f;
    }
    // ---- online softmax. Lane's 16 keys are 1/4 of the query's 64: the
    // full group max needs a cross-QUAD reduce (lanes lc,lc+16,lc+32,lc+48).
    float smax = -3.0e38f;
#pragma unroll
    for (int tt = 0; tt < 4; tt++)
#pragma unroll
      for (int r = 0; r < 4; r++) smax = fmaxf(smax, s[tt][r]);
    smax = fmaxf(smax, __shfl_xor(smax, 16));
    smax = fmaxf(smax, __shfl_xor(smax, 32));  // now uniform across quads
    float mnew = fmaxf(mi, smax);
    float alpha = __expf(mi - mnew);  // mi uniform across quads (inductively)
    mi = mnew;
    float rs = 0.f;
#pragma unroll
    for (int tt = 0; tt < 4; tt++) {
      union { u16 h[4]; u64 d; } pk;
#pragma unroll
      for (int r = 0; r < 4; r++) {
        float p = __expf(s[tt][r] - mnew);
        rs += p;
        pk.h[r] = f2bf(p);
      }
      *(u64*)&Ps[w][lc][tt * 16 + quad * 4] = pk.d;  // Ps[query][key-local]
    }
    li = li * alpha + rs;  // per-lane PARTIAL (this quad's keys); alphas uniform
#pragma unroll
    for (int d = 0; d < 4; d++) o[d] *= alpha;  // o cols = query lc
    // P B-frags: B[n=query=lc][k=key=quad*8+j] (same-wave lockstep DS order)
    bf16x8 pf0 = *(const bf16x8*)&Ps[w][lc][quad * 8];
    bf16x8 pf1 = *(const bf16x8*)&Ps[w][lc][32 + quad * 8];
    // O^T += V^T * P^T : A = V^T rows (m=d), B = P rows (n=query)
#pragma unroll
    for (int dd = 0; dd < 4; dd++) {
      const int R = dd * 16 + lc;
      bf16x8 va0 = *(const bf16x8*)&Vs[R][(quad ^ rx) * 8];
      bf16x8 va1 = *(const bf16x8*)&Vs[R][((4 + quad) ^ rx) * 8];
      o[dd] = MFMA(va0, pf0, o[dd], 0, 0, 0);
      o[dd] = MFMA(va1, pf1, o[dd], 0, 0, 0);
    }
  }
  // li currently holds this quad's partial sum -> reduce across quads once
  li += __shfl_xor(li, 16);
  li += __shfl_xor(li, 32);
  const float rli = 1.0f / li;
  const int b = bh >> 4, hh = bh & 15;
  const size_t obase = ((size_t)(b * 2048 + tq)) * 1024 + hh * 64 + quad * 4;
#pragma unroll
  for (int dd = 0; dd < 4; dd++) {
    ushort4 ov;
    ov.x = f2bf(o[dd][0] * rli);
    ov.y = f2bf(o[dd][1] * rli);
    ov.z = f2bf(o[dd][2] * rli);
    ov.w = f2bf(o[dd][3] * rli);
    *(ushort4*)&O16[obase + dd * 16] = ov;
  }
}

extern "C" void kernel_launch(void* const* d_in, const int* in_sizes, int n_in,
                              void* d_out, int out_size, void* d_ws, size_t ws_size,
                              hipStream_t stream) {
  const float* x  = (const float*)d_in[0];
  const float* wq = (const float*)d_in[1];
  const float* wk = (const float*)d_in[2];
  const float* wv = (const float*)d_in[3];
  const float* wo = (const float*)d_in[4];

  char* w = (char*)d_ws;
  const size_t MB = 1u << 20;
  u16* Xh  = (u16*)(w + 0 * MB);   // 8MB; dead after projections -> O16 reuses
  u16* Xl  = (u16*)(w + 8 * MB);
  u16* Wqh = (u16*)(w + 16 * MB);
  u16* Wql = (u16*)(w + 18 * MB);
  u16* Wkh = (u16*)(w + 20 * MB);
  u16* Wkl = (u16*)(w + 22 * MB);
  u16* Wvt = (u16*)(w + 24 * MB);
  u16* Wot = (u16*)(w + 26 * MB);
  u16* Qhb = (u16*)(w + 28 * MB);  // [32][2048][64] bf16
  u16* Qlb = (u16*)(w + 36 * MB);
  u16* Khb = (u16*)(w + 44 * MB);
  u16* Klb = (u16*)(w + 52 * MB);
  u16* Vtb = (u16*)(w + 60 * MB);  // [32][64][2048] bf16
  u16* O16 = (u16*)(w + 0 * MB);   // reuse Xh region

  hipLaunchKernelGGL(split_cast, dim3(4096), dim3(256), 0, stream, x, Xh, Xl, 4194304);
  dim3 tb(32, 8), tg(32, 32);
  hipLaunchKernelGGL(transpose_cast_split, tg, tb, 0, stream, wq, Wqh, Wql);
  hipLaunchKernelGGL(transpose_cast_split, tg, tb, 0, stream, wk, Wkh, Wkl);
  hipLaunchKernelGGL(transpose_cast, tg, tb, 0, stream, wv, Wvt);
  hipLaunchKernelGGL(transpose_cast, tg, tb, 0, stream, wo, Wot);

  hipLaunchKernelGGL(gemm_qkv, dim3(8, 32, 3), dim3(256), 0, stream,
                     Xh, Xl, Wqh, Wql, Wkh, Wkl, Wvt, Qhb, Qlb, Khb, Klb, Vtb);

  hipLaunchKernelGGL(attn, dim3(1024), dim3(256), 0, stream,
                     Qhb, Qlb, Khb, Klb, Vtb, O16);

  hipLaunchKernelGGL(gemm_out, dim3(8, 64), dim3(256), 0, stream, O16, Wot, (float*)d_out);
}

// Round 10
// 214.251 us; speedup vs baseline: 1.9269x; 1.0507x over previous
//
#include <hip/hip_runtime.h>

// MuliHeadedMaskedSelfAttention: B=2, T=2048, C=1024, H=16, DK=64, OUT=1024
// Logit path (Q/K projection, QK^T) in split-bf16 (3-term MFMA); V/P/O bf16.
// Q pre-scaled by 8 (faithful sqrt(d_k) MULTIPLY).
// R10: fused prep kernel (1 launch for cast+transposes); attn v7 = v6 +
// double-buffered K/V LDS pipeline (1 barrier/group, glds prefetch in flight
// across the whole compute phase).

typedef unsigned short u16;
typedef unsigned int u32;
typedef unsigned long long u64;
typedef __attribute__((ext_vector_type(8))) short bf16x8;
typedef __attribute__((ext_vector_type(4))) float f32x4;

__device__ inline u16 f2bf(float f) {
  union { float f; unsigned u; } v; v.f = f;
  unsigned r = v.u + 0x7FFFu + ((v.u >> 16) & 1u);  // RNE
  return (u16)(r >> 16);
}
__device__ inline float bf2f(u16 h) {
  union { unsigned u; float f; } v; v.u = ((unsigned)h) << 16;
  return v.f;
}
__device__ inline void glds16(const u16* g, u16* s) {
  __builtin_amdgcn_global_load_lds(
      (const __attribute__((address_space(1))) u32*)g,
      (__attribute__((address_space(3))) u32*)s, 16, 0, 0);
}
#define MFMA __builtin_amdgcn_mfma_f32_16x16x32_bf16

// ---- fused prologue. z=0: split-cast x (1024 blocks x 4096 elems).
// z=1,2: split-transpose wq,wk. z=3,4: plain transpose wv,wo.
__global__ __launch_bounds__(256) void prep(
    const float* __restrict__ x,
    const float* __restrict__ wq, const float* __restrict__ wk,
    const float* __restrict__ wv, const float* __restrict__ wo,
    u16* __restrict__ Xh, u16* __restrict__ Xl,
    u16* __restrict__ Wqh, u16* __restrict__ Wql,
    u16* __restrict__ Wkh, u16* __restrict__ Wkl,
    u16* __restrict__ Wvt, u16* __restrict__ Wot) {
  const int z = blockIdx.z;
  const int tid = threadIdx.x;
  if (z == 0) {
    const int bid = blockIdx.y * 32 + blockIdx.x;
#pragma unroll
    for (int k = 0; k < 4; k++) {
      int i = bid * 4096 + k * 1024 + tid * 4;
      float4 v = *(const float4*)(x + i);
      ushort4 h, l;
      h.x = f2bf(v.x); l.x = f2bf(v.x - bf2f(h.x));
      h.y = f2bf(v.y); l.y = f2bf(v.y - bf2f(h.y));
      h.z = f2bf(v.z); l.z = f2bf(v.z - bf2f(h.z));
      h.w = f2bf(v.w); l.w = f2bf(v.w - bf2f(h.w));
      *(ushort4*)(Xh + i) = h;
      *(ushort4*)(Xl + i) = l;
    }
    return;
  }
  __shared__ float tile[32][33];
  const float* W = (z == 1) ? wq : (z == 2) ? wk : (z == 3) ? wv : wo;
  const int bx = blockIdx.x * 32, by = blockIdx.y * 32;
  const int tx = tid & 31, ty = tid >> 5;
#pragma unroll
  for (int j = 0; j < 32; j += 8)
    tile[ty + j][tx] = W[(size_t)(by + ty + j) * 1024 + bx + tx];
  __syncthreads();
  if (z <= 2) {
    u16* Th = (z == 1) ? Wqh : Wkh;
    u16* Tl = (z == 1) ? Wql : Wkl;
#pragma unroll
    for (int j = 0; j < 32; j += 8) {
      float v = tile[tx][ty + j];
      u16 h = f2bf(v);
      size_t idx = (size_t)(bx + ty + j) * 1024 + by + tx;
      Th[idx] = h;
      Tl[idx] = f2bf(v - bf2f(h));
    }
  } else {
    u16* T = (z == 3) ? Wvt : Wot;
#pragma unroll
    for (int j = 0; j < 32; j += 8)
      T[(size_t)(bx + ty + j) * 1024 + by + tx] = f2bf(tile[tx][ty + j]);
  }
}

// ---- fused QKV projection. 128x128 tile, BK=32, global_load_lds staging.
// z=0: Q (split, scale 8), z=1: K (split), z=2: V (plain, V^T out).
__global__ __launch_bounds__(256) void gemm_qkv(
    const u16* __restrict__ Xh, const u16* __restrict__ Xl,
    const u16* __restrict__ Wqh, const u16* __restrict__ Wql,
    const u16* __restrict__ Wkh, const u16* __restrict__ Wkl,
    const u16* __restrict__ Wvt,
    u16* __restrict__ Qh, u16* __restrict__ Ql,
    u16* __restrict__ Kh, u16* __restrict__ Kl,
    u16* __restrict__ Vt) {
  __shared__ u16 S[4][128][32];
  const int K = 1024;
  const int z = blockIdx.z;
  const bool split = (z < 2);
  const u16* Bh = (z == 0) ? Wqh : (z == 1) ? Wkh : Wvt;
  const u16* Bl = (z == 0) ? Wql : Wkl;
  const int tid = threadIdx.x;
  const int lane = tid & 63, wv = tid >> 6;
  const int quad = lane >> 4, lc = lane & 15;
  const int m0 = blockIdx.y * 128, n0 = blockIdx.x * 128;
  const int wm = (wv >> 1) * 64, wn = (wv & 1) * 64;
  const int lrow = lane >> 2, lk = (lane & 3) * 8;
  const u16* a0p = Xh + (size_t)(m0 + wv * 32 + lrow) * K + lk;
  const u16* a1p = a0p + 16 * K;
  const u16* al0p = Xl + (size_t)(m0 + wv * 32 + lrow) * K + lk;
  const u16* al1p = al0p + 16 * K;
  const u16* b0p = Bh + (size_t)(n0 + wv * 32 + lrow) * K + lk;
  const u16* b1p = b0p + 16 * K;
  const u16* bl0p = split ? (Bl + (size_t)(n0 + wv * 32 + lrow) * K + lk) : b0p;
  const u16* bl1p = bl0p + 16 * K;
  u16* sA0 = &S[0][wv * 32][0];      u16* sA1 = &S[0][wv * 32 + 16][0];
  u16* sAl0 = &S[1][wv * 32][0];     u16* sAl1 = &S[1][wv * 32 + 16][0];
  u16* sB0 = &S[2][wv * 32][0];      u16* sB1 = &S[2][wv * 32 + 16][0];
  u16* sBl0 = &S[3][wv * 32][0];     u16* sBl1 = &S[3][wv * 32 + 16][0];
  f32x4 acc[4][4];
#pragma unroll
  for (int i = 0; i < 4; i++)
#pragma unroll
    for (int j = 0; j < 4; j++) acc[i][j] = (f32x4){0.f, 0.f, 0.f, 0.f};
  for (int kc = 0; kc < K; kc += 32) {
    __syncthreads();
    glds16(a0p + kc, sA0); glds16(a1p + kc, sA1);
    glds16(b0p + kc, sB0); glds16(b1p + kc, sB1);
    if (split) {
      glds16(al0p + kc, sAl0); glds16(al1p + kc, sAl1);
      glds16(bl0p + kc, sBl0); glds16(bl1p + kc, sBl1);
    }
    __syncthreads();
    bf16x8 ah[4], al[4];
#pragma unroll
    for (int mt = 0; mt < 4; mt++)
      ah[mt] = *(const bf16x8*)&S[0][wm + mt * 16 + lc][quad * 8];
    if (split) {
#pragma unroll
      for (int mt = 0; mt < 4; mt++)
        al[mt] = *(const bf16x8*)&S[1][wm + mt * 16 + lc][quad * 8];
    }
#pragma unroll
    for (int nt = 0; nt < 4; nt++) {
      bf16x8 bfh = *(const bf16x8*)&S[2][wn + nt * 16 + lc][quad * 8];
#pragma unroll
      for (int mt = 0; mt < 4; mt++)
        acc[mt][nt] = MFMA(ah[mt], bfh, acc[mt][nt], 0, 0, 0);
      if (split) {
        bf16x8 bfl = *(const bf16x8*)&S[3][wn + nt * 16 + lc][quad * 8];
#pragma unroll
        for (int mt = 0; mt < 4; mt++) {
          acc[mt][nt] = MFMA(ah[mt], bfl, acc[mt][nt], 0, 0, 0);
          acc[mt][nt] = MFMA(al[mt], bfh, acc[mt][nt], 0, 0, 0);
        }
      }
    }
  }
  const int rb = quad * 4;
  if (z == 2) {
#pragma unroll
    for (int mt = 0; mt < 4; mt++)
#pragma unroll
      for (int nt = 0; nt < 4; nt++)
#pragma unroll
        for (int r = 0; r < 4; r++) {
          int m = m0 + wm + mt * 16 + rb + r, n = n0 + wn + nt * 16 + lc;
          int b = m >> 11, t = m & 2047, h = n >> 6, d = n & 63;
          Vt[((size_t)(b * 16 + h) * 64 + d) * 2048 + t] = f2bf(acc[mt][nt][r]);
        }
  } else {
    u16* Ch = (z == 0) ? Qh : Kh;
    u16* Cl = (z == 0) ? Ql : Kl;
    const float scale = (z == 0) ? 8.0f : 1.0f;  // fold sqrt(d_k) into Q ONLY
#pragma unroll
    for (int mt = 0; mt < 4; mt++)
#pragma unroll
      for (int nt = 0; nt < 4; nt++)
#pragma unroll
        for (int r = 0; r < 4; r++) {
          int m = m0 + wm + mt * 16 + rb + r, n = n0 + wn + nt * 16 + lc;
          int b = m >> 11, t = m & 2047, h = n >> 6, d = n & 63;
          float v = acc[mt][nt][r] * scale;
          u16 hv = f2bf(v);
          size_t idx = ((size_t)(b * 16 + h) * 2048 + t) * 64 + d;
          Ch[idx] = hv;
          Cl[idx] = f2bf(v - bf2f(hv));
        }
  }
}

// ---- output GEMM: C[4096,1024] fp32 = O16[4096,1024] * Wot[1024,1024]^T.
__global__ __launch_bounds__(256) void gemm_out(const u16* __restrict__ A,
                                                const u16* __restrict__ Bt,
                                                float* __restrict__ C) {
  __shared__ u16 Sa[64][32], Sb[128][32];
  const int K = 1024, N = 1024;
  const int tid = threadIdx.x;
  const int lane = tid & 63, wv = tid >> 6;
  const int quad = lane >> 4, lc = lane & 15;
  const int m0 = blockIdx.y * 64, n0 = blockIdx.x * 128;
  const int wm = (wv >> 1) * 32, wn = (wv & 1) * 64;
  const int lrow = lane >> 2, lk = (lane & 3) * 8;
  const u16* ap = A + (size_t)(m0 + wv * 16 + lrow) * K + lk;
  const u16* b0p = Bt + (size_t)(n0 + wv * 32 + lrow) * K + lk;
  const u16* b1p = b0p + 16 * K;
  u16* sA = &Sa[wv * 16][0];
  u16* sB0 = &Sb[wv * 32][0];
  u16* sB1 = &Sb[wv * 32 + 16][0];
  f32x4 acc[2][4];
#pragma unroll
  for (int i = 0; i < 2; i++)
#pragma unroll
    for (int j = 0; j < 4; j++) acc[i][j] = (f32x4){0.f, 0.f, 0.f, 0.f};
  for (int kc = 0; kc < K; kc += 32) {
    __syncthreads();
    glds16(ap + kc, sA);
    glds16(b0p + kc, sB0);
    glds16(b1p + kc, sB1);
    __syncthreads();
    bf16x8 ah[2];
#pragma unroll
    for (int mt = 0; mt < 2; mt++)
      ah[mt] = *(const bf16x8*)&Sa[wm + mt * 16 + lc][quad * 8];
#pragma unroll
    for (int nt = 0; nt < 4; nt++) {
      bf16x8 bfh = *(const bf16x8*)&Sb[wn + nt * 16 + lc][quad * 8];
#pragma unroll
      for (int mt = 0; mt < 2; mt++)
        acc[mt][nt] = MFMA(ah[mt], bfh, acc[mt][nt], 0, 0, 0);
    }
  }
#pragma unroll
  for (int mt = 0; mt < 2; mt++)
#pragma unroll
    for (int nt = 0; nt < 4; nt++)
#pragma unroll
      for (int r = 0; r < 4; r++)
        C[(size_t)(m0 + wm + mt * 16 + quad * 4 + r) * N + n0 + wn + nt * 16 + lc] =
            acc[mt][nt][r];
}

// ---- flash attention v7: transposed tiles + double-buffered K/V pipeline.
// One barrier per 64-key group; glds(g+1) stays in flight across compute(g).
__global__ __launch_bounds__(256, 2) void attn(const u16* __restrict__ Qh,
                                               const u16* __restrict__ Ql,
                                               const u16* __restrict__ Kh,
                                               const u16* __restrict__ Kl,
                                               const u16* __restrict__ Vt,
                                               u16* __restrict__ O16) {
  __shared__ u16 Khs[2][64][64], Kls[2][64][64], Vs[2][64][64];
  __shared__ u16 Ps[4][16][72];  // [wave][query][key-local], 2-way banks (free)
  const int tid = threadIdx.x;
  const int lane = tid & 63, w = tid >> 6;
  const int quad = lane >> 4, lc = lane & 15;
  const int i = blockIdx.x;
  const int bh = i & 31;            // consecutive blocks -> different XCDs
  const int qb = 31 - (i >> 5);     // longest qb first
  const int ng = qb + 1;            // 64-key groups
  const int tq = qb * 64 + w * 16 + lc;  // THIS LANE'S query row
  const size_t kbase = (size_t)bh * 2048 * 64;
  const size_t vbase = (size_t)bh * 64 * 2048;
  const size_t qoff = kbase + (size_t)tq * 64 + quad * 8;
  bf16x8 qh0 = *(const bf16x8*)(Qh + qoff);
  bf16x8 qh1 = *(const bf16x8*)(Qh + qoff + 32);
  bf16x8 ql0 = *(const bf16x8*)(Ql + qoff);
  bf16x8 ql1 = *(const bf16x8*)(Ql + qoff + 32);
  // staging roles: lane -> (row srow, swizzled chunk scol) of 8-row slabs
  const int srow = lane >> 3;
  const int scol = (lane & 7) ^ srow;
  const u16* kg0 = Kh + kbase + (size_t)(w * 16 + srow) * 64 + scol * 8;
  const u16* lg0 = Kl + kbase + (size_t)(w * 16 + srow) * 64 + scol * 8;
  const u16* vg0 = Vt + vbase + (size_t)(w * 16 + srow) * 2048 + scol * 8;

  float mi = -3.0e38f, li = 0.f;
  f32x4 o[4];
#pragma unroll
  for (int d = 0; d < 4; d++) o[d] = (f32x4){0.f, 0.f, 0.f, 0.f};
  const int rx = lc & 7;  // read-side XOR component (row&7 = lc&7)

  // prefetch group 0 into buffer 0
  {
    glds16(kg0, &Khs[0][w * 16][0]); glds16(kg0 + 8 * 64, &Khs[0][w * 16 + 8][0]);
    glds16(lg0, &Kls[0][w * 16][0]); glds16(lg0 + 8 * 64, &Kls[0][w * 16 + 8][0]);
    glds16(vg0, &Vs[0][w * 16][0]);  glds16(vg0 + 8 * 2048, &Vs[0][w * 16 + 8][0]);
  }
  for (int g = 0; g < ng; g++) {
    const int buf = g & 1;
    const int z0 = g * 64;
    __syncthreads();  // drains glds(g); all waves done reading buf^1 (grp g-1)
    if (g + 1 < ng) {  // prefetch g+1 into the other buffer; in flight all group
      const int zn = (g + 1) * 64;
      const int nb = buf ^ 1;
      glds16(kg0 + (size_t)zn * 64, &Khs[nb][w * 16][0]);
      glds16(kg0 + (size_t)zn * 64 + 8 * 64, &Khs[nb][w * 16 + 8][0]);
      glds16(lg0 + (size_t)zn * 64, &Kls[nb][w * 16][0]);
      glds16(lg0 + (size_t)zn * 64 + 8 * 64, &Kls[nb][w * 16 + 8][0]);
      glds16(vg0 + zn, &Vs[nb][w * 16][0]);
      glds16(vg0 + zn + 8 * 2048, &Vs[nb][w * 16 + 8][0]);
    }
    // S^T tiles: rows = keys, cols = queries. Lane holds keys tt*16+quad*4+r.
    f32x4 s[4];
#pragma unroll
    for (int tt = 0; tt < 4; tt++) {
      const int R = tt * 16 + lc;
      bf16x8 kh0 = *(const bf16x8*)&Khs[buf][R][(quad ^ rx) * 8];
      bf16x8 kh1 = *(const bf16x8*)&Khs[buf][R][((4 + quad) ^ rx) * 8];
      bf16x8 kl0 = *(const bf16x8*)&Kls[buf][R][(quad ^ rx) * 8];
      bf16x8 kl1 = *(const bf16x8*)&Kls[buf][R][((4 + quad) ^ rx) * 8];
      f32x4 sv = (f32x4){0.f, 0.f, 0.f, 0.f};
      sv = MFMA(kh0, qh0, sv, 0, 0, 0);
      sv = MFMA(kh1, qh1, sv, 0, 0, 0);
      sv = MFMA(kh0, ql0, sv, 0, 0, 0);
      sv = MFMA(kh1, ql1, sv, 0, 0, 0);
      sv = MFMA(kl0, qh0, sv, 0, 0, 0);
      sv = MFMA(kl1, qh1, sv, 0, 0, 0);
      s[tt] = sv;
    }
    if (g == ng - 1) {  // only the final group straddles the diagonal
#pragma unroll
      for (int tt = 0; tt < 4; tt++)
#pragma unroll
        for (int r = 0; r < 4; r++)
          if (z0 + tt * 16 + quad * 4 + r > tq) s[tt][r] = -3.0e38f;
    }
    // online softmax: cross-QUAD max (2 shuffles) for consistent normalization
    float smax = -3.0e38f;
#pragma unroll
    for (int tt = 0; tt < 4; tt++)
#pragma unroll
      for (int r = 0; r < 4; r++) smax = fmaxf(smax, s[tt][r]);
    smax = fmaxf(smax, __shfl_xor(smax, 16));
    smax = fmaxf(smax, __shfl_xor(smax, 32));
    float mnew = fmaxf(mi, smax);
    float alpha = __expf(mi - mnew);
    mi = mnew;
    float rs = 0.f;
#pragma unroll
    for (int tt = 0; tt < 4; tt++) {
      union { u16 h[4]; u64 d; } pk;
#pragma unroll
      for (int r = 0; r < 4; r++) {
        float p = __expf(s[tt][r] - mnew);
        rs += p;
        pk.h[r] = f2bf(p);
      }
      *(u64*)&Ps[w][lc][tt * 16 + quad * 4] = pk.d;
    }
    li = li * alpha + rs;  // per-lane partial; alphas uniform across quads
#pragma unroll
    for (int d = 0; d < 4; d++) o[d] *= alpha;
    // P B-frags (per-wave LDS, lockstep DS ordering)
    bf16x8 pf0 = *(const bf16x8*)&Ps[w][lc][quad * 8];
    bf16x8 pf1 = *(const bf16x8*)&Ps[w][lc][32 + quad * 8];
#pragma unroll
    for (int dd = 0; dd < 4; dd++) {
      const int R = dd * 16 + lc;
      bf16x8 va0 = *(const bf16x8*)&Vs[buf][R][(quad ^ rx) * 8];
      bf16x8 va1 = *(const bf16x8*)&Vs[buf][R][((4 + quad) ^ rx) * 8];
      o[dd] = MFMA(va0, pf0, o[dd], 0, 0, 0);
      o[dd] = MFMA(va1, pf1, o[dd], 0, 0, 0);
    }
  }
  li += __shfl_xor(li, 16);
  li += __shfl_xor(li, 32);
  const float rli = 1.0f / li;
  const int b = bh >> 4, hh = bh & 15;
  const size_t obase = ((size_t)(b * 2048 + tq)) * 1024 + hh * 64 + quad * 4;
#pragma unroll
  for (int dd = 0; dd < 4; dd++) {
    ushort4 ov;
    ov.x = f2bf(o[dd][0] * rli);
    ov.y = f2bf(o[dd][1] * rli);
    ov.z = f2bf(o[dd][2] * rli);
    ov.w = f2bf(o[dd][3] * rli);
    *(ushort4*)&O16[obase + dd * 16] = ov;
  }
}

extern "C" void kernel_launch(void* const* d_in, const int* in_sizes, int n_in,
                              void* d_out, int out_size, void* d_ws, size_t ws_size,
                              hipStream_t stream) {
  const float* x  = (const float*)d_in[0];
  const float* wq = (const float*)d_in[1];
  const float* wk = (const float*)d_in[2];
  const float* wv = (const float*)d_in[3];
  const float* wo = (const float*)d_in[4];

  char* w = (char*)d_ws;
  const size_t MB = 1u << 20;
  u16* Xh  = (u16*)(w + 0 * MB);   // 8MB; dead after projections -> O16 reuses
  u16* Xl  = (u16*)(w + 8 * MB);
  u16* Wqh = (u16*)(w + 16 * MB);
  u16* Wql = (u16*)(w + 18 * MB);
  u16* Wkh = (u16*)(w + 20 * MB);
  u16* Wkl = (u16*)(w + 22 * MB);
  u16* Wvt = (u16*)(w + 24 * MB);
  u16* Wot = (u16*)(w + 26 * MB);
  u16* Qhb = (u16*)(w + 28 * MB);  // [32][2048][64] bf16
  u16* Qlb = (u16*)(w + 36 * MB);
  u16* Khb = (u16*)(w + 44 * MB);
  u16* Klb = (u16*)(w + 52 * MB);
  u16* Vtb = (u16*)(w + 60 * MB);  // [32][64][2048] bf16
  u16* O16 = (u16*)(w + 0 * MB);   // reuse Xh region

  hipLaunchKernelGGL(prep, dim3(32, 32, 5), dim3(256), 0, stream,
                     x, wq, wk, wv, wo, Xh, Xl, Wqh, Wql, Wkh, Wkl, Wvt, Wot);

  hipLaunchKernelGGL(gemm_qkv, dim3(8, 32, 3), dim3(256), 0, stream,
                     Xh, Xl, Wqh, Wql, Wkh, Wkl, Wvt, Qhb, Qlb, Khb, Klb, Vtb);

  hipLaunchKernelGGL(attn, dim3(1024), dim3(256), 0, stream,
                     Qhb, Qlb, Khb, Klb, Vtb, O16);

  hipLaunchKernelGGL(gemm_out, dim3(8, 64), dim3(256), 0, stream, O16, Wot, (float*)d_out);
}